// Round 15
// baseline (526.478 us; speedup 1.0000x reference)
//
#include <hip/hip_runtime.h>
#include <stdint.h>

// SoftmaxAttention: x[2,2048,2048] f32, w_qkv[6144,2048] f32, w_out[2048,2048] f32
// out[2,2048,2048] f32.  All matmul-shaped compute via bf16 MFMA 16x16x32.

typedef __attribute__((ext_vector_type(8))) short bf16x8;
typedef __attribute__((ext_vector_type(8))) unsigned short u16x8;
typedef __attribute__((ext_vector_type(4))) unsigned short u16x4;
typedef __attribute__((ext_vector_type(4))) float f32x4;

#define MFMA16(a, b, c) __builtin_amdgcn_mfma_f32_16x16x32_bf16((a), (b), (c), 0, 0, 0)

__device__ __forceinline__ unsigned short f2bf(float f) {
  union { float f; uint32_t u; } v; v.f = f;
  uint32_t r = v.u + 0x7FFFu + ((v.u >> 16) & 1u);  // RNE
  return (unsigned short)(r >> 16);
}

__device__ __forceinline__ void gld_lds16(const unsigned short* g, unsigned short* lds) {
  __builtin_amdgcn_global_load_lds(
      (const __attribute__((address_space(1))) void*)g,
      (__attribute__((address_space(3))) void*)lds, 16, 0, 0);
}

// ---------------------------------------------------------------- cvt f32->bf16
__device__ __forceinline__ void cvt8(const float* __restrict__ in,
                                     unsigned short* __restrict__ out, int i) {
  float4 a = reinterpret_cast<const float4*>(in)[i * 2];
  float4 b = reinterpret_cast<const float4*>(in)[i * 2 + 1];
  u16x8 o;
  o[0] = f2bf(a.x); o[1] = f2bf(a.y); o[2] = f2bf(a.z); o[3] = f2bf(a.w);
  o[4] = f2bf(b.x); o[5] = f2bf(b.y); o[6] = f2bf(b.z); o[7] = f2bf(b.w);
  reinterpret_cast<u16x8*>(out)[i] = o;
}

__global__ __launch_bounds__(256) void cvt_all(const float* __restrict__ x,
                                               const float* __restrict__ wq,
                                               const float* __restrict__ wo,
                                               unsigned short* __restrict__ xb,
                                               unsigned short* __restrict__ wqb,
                                               unsigned short* __restrict__ wob) {
  const int stride = gridDim.x * blockDim.x;
  const int t0 = blockIdx.x * blockDim.x + threadIdx.x;
  for (int i = t0; i < 1048576; i += stride) cvt8(x, xb, i);
  for (int i = t0; i < 1572864; i += stride) cvt8(wq, wqb, i);
  for (int i = t0; i < 524288; i += stride) cvt8(wo, wob, i);
}

// ============== 128x128 bf16 GEMM core, BK=64 single-buffer (B^T) =============
// 256 thr, 4 waves (2x2 of 64x64).  Per K-step(64): 8 gld_lds + barrier +
// (8 ds_read + 16 MFMA) x2 + barrier.  T2 swizzle g_lds = g ^ (row&7), via
// pre-swizzled global source (rule #21) + XOR'd fragment read: 0 conflicts.
__device__ __forceinline__ void gemm128_core(const unsigned short* __restrict__ A,
                                             const unsigned short* __restrict__ Bt,
                                             int K, int brow, int bcol,
                                             unsigned short* lds_a, unsigned short* lds_b,
                                             f32x4 acc[4][4]) {
  const int tid = threadIdx.x;
  const int l   = tid & 63;
  const int w   = tid >> 6;
  const int wr  = (w >> 1) << 6;
  const int wc  = (w & 1) << 6;

  const int srow = tid >> 3;
  const int gsrc = (tid & 7) ^ (srow & 7);
  const unsigned short* gA0 = A  + (size_t)(brow + srow) * K + 8 * gsrc;
  const unsigned short* gB0 = Bt + (size_t)(bcol + srow) * K + 8 * gsrc;
  unsigned short* dA0 = lds_a + tid * 8;
  unsigned short* dB0 = lds_b + tid * 8;

  const int fm = l & 15;
  const int q  = l >> 4;

  for (int k0 = 0; k0 < K; k0 += 64) {
#pragma unroll
    for (int c = 0; c < 4; c++)
      gld_lds16(gA0 + (size_t)c * 32 * K + k0, dA0 + c * 2048);
#pragma unroll
    for (int c = 0; c < 4; c++)
      gld_lds16(gB0 + (size_t)c * 32 * K + k0, dB0 + c * 2048);
    __syncthreads();  // drains vmcnt(0): staged data visible
#pragma unroll
    for (int ks = 0; ks < 2; ks++) {
      const int goff = 8 * ((ks * 4 + q) ^ (fm & 7));
      bf16x8 af[4], bfv[4];
#pragma unroll
      for (int i = 0; i < 4; i++)
        af[i] = *(const bf16x8*)&lds_a[(wr + i * 16 + fm) * 64 + goff];
#pragma unroll
      for (int j = 0; j < 4; j++)
        bfv[j] = *(const bf16x8*)&lds_b[(wc + j * 16 + fm) * 64 + goff];
#pragma unroll
      for (int i = 0; i < 4; i++)
#pragma unroll
        for (int j = 0; j < 4; j++)
          acc[i][j] = MFMA16(af[i], bfv[j], acc[i][j]);
    }
    __syncthreads();
  }
}

// --------------------------------------------------------------- QKV projection
// launch_bounds(256,5): cap VGPR at ~102 -> 5 blocks/CU (5 x 32KB = 160KB LDS,
// exactly the pool).  Occupancy 21% -> ~26%; more resident waves hide the
// per-K-step barrier drain (the R1-structure TLP mechanism, m114).
__global__ __launch_bounds__(256, 5) void gemm_qkv(const unsigned short* __restrict__ xb,
                                                   const unsigned short* __restrict__ wqb,
                                                   unsigned short* __restrict__ Qb,
                                                   unsigned short* __restrict__ Kb,
                                                   unsigned short* __restrict__ Vtb) {
  __shared__ alignas(16) unsigned short lds_a[128 * 64];
  __shared__ alignas(16) unsigned short lds_b[128 * 64];
  f32x4 acc[4][4];
#pragma unroll
  for (int i = 0; i < 4; i++)
#pragma unroll
    for (int j = 0; j < 4; j++) acc[i][j] = (f32x4){0.f, 0.f, 0.f, 0.f};

  const int brow = blockIdx.x << 7;   // 32 row tiles (fastest-varying)
  const int bcol = blockIdx.y << 7;   // 48 col tiles
  gemm128_core(xb, wqb, 2048, brow, bcol, lds_a, lds_b, acc);

  const int l = threadIdx.x & 63;
  const int w = threadIdx.x >> 6;
  const int wr = (w >> 1) << 6, wc = (w & 1) << 6;
  const int which = bcol >> 11;                         // 0=Q 1=K 2=V (block-uniform)
  const float qs = (which == 0) ? 0.12752585f : 1.0f;   // log2(e)/sqrt(128) into Q
  const int bh = ((brow >> 11) << 4) | ((bcol >> 7) & 15);
  const int tbase = (brow & 2047) + wr + ((l >> 4) << 2);

#pragma unroll
  for (int i = 0; i < 4; i++) {
    const int t0 = tbase + i * 16;
#pragma unroll
    for (int j = 0; j < 4; j++) {
      const int d = wc + j * 16 + (l & 15);
      if (which == 2) {
        u16x4 pk;
#pragma unroll
        for (int r = 0; r < 4; r++) pk[r] = f2bf(acc[i][j][r]);
        *reinterpret_cast<u16x4*>(&Vtb[((size_t)bh * 128 + d) * 2048 + t0]) = pk;
      } else {
        unsigned short* dst = (which == 0 ? Qb : Kb) + ((size_t)bh * 2048 + t0) * 128 + d;
#pragma unroll
        for (int r = 0; r < 4; r++) dst[(size_t)r * 128] = f2bf(acc[i][j][r] * qs);
      }
    }
  }
}

// -------------------------------------------------------------- output projection
__global__ __launch_bounds__(256, 5) void gemm_out(const unsigned short* __restrict__ yb,
                                                   const unsigned short* __restrict__ wob,
                                                   float* __restrict__ out) {
  __shared__ alignas(16) unsigned short lds_a[128 * 64];
  __shared__ alignas(16) unsigned short lds_b[128 * 64];
  f32x4 acc[4][4];
#pragma unroll
  for (int i = 0; i < 4; i++)
#pragma unroll
    for (int j = 0; j < 4; j++) acc[i][j] = (f32x4){0.f, 0.f, 0.f, 0.f};

  const int brow = blockIdx.x << 7;   // 32 row tiles (fastest-varying)
  const int bcol = blockIdx.y << 7;   // 16 col tiles
  gemm128_core(yb, wob, 2048, brow, bcol, lds_a, lds_b, acc);

  const int l = threadIdx.x & 63;
  const int w = threadIdx.x >> 6;
  const int wr = (w >> 1) << 6, wc = (w & 1) << 6;
#pragma unroll
  for (int i = 0; i < 4; i++) {
    const int m0 = brow + wr + i * 16 + ((l >> 4) << 2);
#pragma unroll
    for (int j = 0; j < 4; j++) {
      const int n = bcol + wc + j * 16 + (l & 15);
#pragma unroll
      for (int r = 0; r < 4; r++) out[(size_t)(m0 + r) * 2048 + n] = acc[i][j][r];
    }
  }
}

// ------------------------------------------------------------------ flash attn
// R14 structure (proven best): 8-wave split of the causal pair, waves 0-3 own
// tile j, waves 4-7 own 31-j.  K,V double-buffered; one vmcnt(0)+barrier per
// kv-step.  Defer-max + deferred sum.  Q pre-scaled; P stored by truncation;
// P-slot bijection; reciprocal epilogue.
__device__ __forceinline__ void stage_kv64(const unsigned short* __restrict__ Kg,
                                           const unsigned short* __restrict__ Vg,
                                           int kv0, unsigned short* dk,
                                           unsigned short* dv, int tid) {
#pragma unroll
  for (int c = 0; c < 2; c++) {
    int s = c * 512 + tid;
    int row = s >> 4, g = s & 15;
    gld_lds16(&Kg[(size_t)(kv0 + row) * 128 + 8 * (g ^ (row & 7))], &dk[s * 8]);
  }
#pragma unroll
  for (int c = 0; c < 2; c++) {
    int s = c * 512 + tid;
    int row = s >> 3, g = s & 7;
    gld_lds16(&Vg[(size_t)row * 2048 + kv0 + 8 * (g ^ (row & 7))], &dv[s * 8]);
  }
}

// one q-tile's contribution for one kv-tile (QK^T -> online softmax -> PV)
__device__ __forceinline__ void attn_tile_step(const bf16x8 qf[4], f32x4 yacc[8],
                                               float mrow[4], float lsum[4],
                                               int qw0, int kv0,
                                               const unsigned short* kb,
                                               const unsigned short* vb,
                                               unsigned short* pw, int l) {
  // S = Q K^T : 16 MFMA (Q pre-scaled by log2(e)/sqrt(128))
  f32x4 sfr[4];
  __builtin_amdgcn_s_setprio(1);
#pragma unroll
  for (int kt = 0; kt < 4; kt++) {
    const int kr = kt * 16 + (l & 15);
    f32x4 s4 = (f32x4){0.f, 0.f, 0.f, 0.f};
#pragma unroll
    for (int ds = 0; ds < 4; ds++) {
      bf16x8 kfr = *(const bf16x8*)&kb[kr * 128 + 8 * (((ds << 2) + (l >> 4)) ^ (kr & 7))];
      s4 = MFMA16(qf[ds], kfr, s4);
    }
    sfr[kt] = s4;
  }
  __builtin_amdgcn_s_setprio(0);
  const bool need_mask = (kv0 + 63 > qw0);
  if (need_mask) {
#pragma unroll
    for (int kt = 0; kt < 4; kt++)
#pragma unroll
      for (int r = 0; r < 4; r++) {
        int qa = qw0 + ((l >> 4) << 2) + r;
        int ka = kv0 + kt * 16 + (l & 15);
        if (ka > qa) sfr[kt][r] = -1e30f;
      }
  }
  // per-lane partial row max (rows at (l>>4)*4 + r, cols on l&15)
  float prmax[4];
#pragma unroll
  for (int r = 0; r < 4; r++)
    prmax[r] = fmaxf(fmaxf(sfr[0][r], sfr[1][r]), fmaxf(sfr[2][r], sfr[3][r]));
  // T13 defer-max, cheap per-lane check: skip shfl reduce AND rescale usually
  bool sm = (prmax[0] <= mrow[0] + 8.f) && (prmax[1] <= mrow[1] + 8.f) &&
            (prmax[2] <= mrow[2] + 8.f) && (prmax[3] <= mrow[3] + 8.f);
  if (!__all(sm)) {
    float f[4];
#pragma unroll
    for (int r = 0; r < 4; r++) {
      float m = prmax[r];
      m = fmaxf(m, __shfl_xor(m, 1));
      m = fmaxf(m, __shfl_xor(m, 2));
      m = fmaxf(m, __shfl_xor(m, 4));
      m = fmaxf(m, __shfl_xor(m, 8));
      float mn = fmaxf(mrow[r], m);
      f[r] = exp2f(mrow[r] - mn);   // row-uniform across the 16 lanes of a row
      mrow[r] = mn;
      lsum[r] *= f[r];
    }
#pragma unroll
    for (int dt = 0; dt < 8; dt++)
#pragma unroll
      for (int r = 0; r < 4; r++) yacc[dt][r] *= f[r];
  }
  // P = exp2(S - m) (bounded by 2^8 when deferred); per-lane deferred sum;
  // bf16 by truncation.  Slot = (k>>3) ^ ((row>>2)<<1): 8 slots/batch.
#pragma unroll
  for (int kt = 0; kt < 4; kt++)
#pragma unroll
    for (int r = 0; r < 4; r++) {
      float p = exp2f(sfr[kt][r] - mrow[r]);
      lsum[r] += p;
      union { float f; uint32_t u; } cc; cc.f = p;
      int row = ((l >> 4) << 2) + r;
      int k = kt * 16 + (l & 15);
      pw[row * 64 + (((k >> 3) ^ ((row >> 2) << 1)) << 3) + (k & 7)] =
          (unsigned short)(cc.u >> 16);
    }
  // cross-lane LDS write->read fence (same wave); rule #18 sched_barrier
  asm volatile("s_waitcnt lgkmcnt(0)" ::: "memory");
  __builtin_amdgcn_sched_barrier(0);
  // PV: 16 MFMA.  A = P, B = V from V^T LDS
  __builtin_amdgcn_s_setprio(1);
#pragma unroll
  for (int ks = 0; ks < 2; ks++) {
    const int prow = l & 15;
    bf16x8 pa = *(const bf16x8*)&pw[prow * 64 +
                                    (((ks * 4 + (l >> 4)) ^ ((prow >> 2) << 1)) << 3)];
#pragma unroll
    for (int dt = 0; dt < 8; dt++) {
      const int d = dt * 16 + (l & 15);
      bf16x8 vv = *(const bf16x8*)&vb[d * 64 + ((((ks << 2) + (l >> 4)) ^ (d & 7)) << 3)];
      yacc[dt] = MFMA16(pa, vv, yacc[dt]);
    }
  }
  __builtin_amdgcn_s_setprio(0);
}

__global__ __launch_bounds__(512, 4) void attn_kernel(const unsigned short* __restrict__ Qb,
                                                      const unsigned short* __restrict__ Kb,
                                                      const unsigned short* __restrict__ Vtb,
                                                      unsigned short* __restrict__ Yb) {
  __shared__ alignas(16) unsigned short lds_k[2][64 * 128];
  __shared__ alignas(16) unsigned short lds_v[2][128 * 64];
  __shared__ alignas(16) unsigned short p_lds[8][16 * 64];  // one per wave

  const int tid = threadIdx.x;
  const int l = tid & 63;
  const int w = tid >> 6;                    // 0..7

  const int bid = blockIdx.x;                // 0..511
  const int xcd = bid & 7;
  const int loc = bid >> 3;                  // 0..63
  const int bh = xcd * 4 + (loc >> 4);       // 0..31 (XCD-grouped KV)
  // complementary length pairing: loc and loc+32 get jidx j and 15-j
  const int jraw = loc & 15;
  const int jidx = (loc < 32) ? jraw : (15 - jraw);

  const int b = bh >> 4, h = bh & 15;

  const unsigned short* Qg = Qb + (size_t)bh * 2048 * 128;
  const unsigned short* Kg = Kb + (size_t)bh * 2048 * 128;
  const unsigned short* Vg = Vtb + (size_t)bh * 128 * 2048;

  // waves 0-3: tile jidx (rows (w&3)*16); waves 4-7: tile 31-jidx
  const int my_j = (w < 4) ? jidx : (31 - jidx);
  const int qw0 = (my_j << 6) + ((w & 3) << 4);

  // Q fragments (A-operand: m = l&15, k = ds*32 + 8*(l>>4))
  bf16x8 qf[4];
#pragma unroll
  for (int ds = 0; ds < 4; ds++)
    qf[ds] = *(const bf16x8*)&Qg[(size_t)(qw0 + (l & 15)) * 128 + ds * 32 + 8 * (l >> 4)];

  f32x4 yacc[8];
#pragma unroll
  for (int dt = 0; dt < 8; dt++) yacc[dt] = (f32x4){0.f, 0.f, 0.f, 0.f};
  float mrow[4], lsum[4];
#pragma unroll
  for (int r = 0; r < 4; r++) { mrow[r] = -1e30f; lsum[r] = 0.f; }

  const int nkv = (31 - jidx) + 1;  // hi tile bound: 17..32 kv-steps

  // prologue: stage tile 0
  stage_kv64(Kg, Vg, 0, lds_k[0], lds_v[0], tid);
  asm volatile("s_waitcnt vmcnt(0)" ::: "memory");
  __syncthreads();

  for (int t = 0; t < nkv; t++) {
    const int kv0 = t << 6;
    const int buf = t & 1;
    if (t + 1 < nkv)
      stage_kv64(Kg, Vg, kv0 + 64, lds_k[buf ^ 1], lds_v[buf ^ 1], tid);

    // hi waves: always active; lo waves: active while kv0 <= qw0+15
    if (kv0 <= qw0 + 15)
      attn_tile_step(qf, yacc, mrow, lsum, qw0, kv0, lds_k[buf], lds_v[buf],
                     p_lds[w], l);

    asm volatile("s_waitcnt vmcnt(0)" ::: "memory");
    __syncthreads();
  }

  // epilogue: reduce deferred sum once, reciprocal, then y into [B,T,C]
  float rinv[4];
#pragma unroll
  for (int r = 0; r < 4; r++) {
    float s = lsum[r];
    s += __shfl_xor(s, 1); s += __shfl_xor(s, 2);
    s += __shfl_xor(s, 4); s += __shfl_xor(s, 8);
    rinv[r] = 1.0f / s;
  }
#pragma unroll
  for (int dt = 0; dt < 8; dt++)
#pragma unroll
    for (int r = 0; r < 4; r++) {
      int qa = qw0 + ((l >> 4) << 2) + r;
      Yb[((size_t)(b * 2048 + qa)) * 2048 + h * 128 + dt * 16 + (l & 15)] =
          f2bf(yacc[dt][r] * rinv[r]);
    }
}

// ---------------------------------------------------------------------- launch
extern "C" void kernel_launch(void* const* d_in, const int* in_sizes, int n_in,
                              void* d_out, int out_size, void* d_ws, size_t ws_size,
                              hipStream_t stream) {
  const float* x    = (const float*)d_in[0];
  const float* wqkv = (const float*)d_in[1];
  const float* wout = (const float*)d_in[2];
  float* out = (float*)d_out;

  // workspace layout (bf16 elements)
  unsigned short* ws  = (unsigned short*)d_ws;
  unsigned short* xb  = ws;                        // 4096*2048
  unsigned short* wqb = xb + (size_t)8388608;      // 6144*2048
  unsigned short* wob = wqb + (size_t)12582912;    // 2048*2048
  unsigned short* Qb  = wob + (size_t)4194304;     // [32,2048,128] (pre-scaled)
  unsigned short* Kb  = Qb + (size_t)8388608;      // [32,2048,128]
  unsigned short* Vtb = Kb + (size_t)8388608;      // [32,128,2048] (transposed)
  unsigned short* Yb  = Vtb + (size_t)8388608;     // [4096,2048]

  cvt_all<<<2048, 256, 0, stream>>>(x, wqkv, wout, xb, wqb, wob);
  gemm_qkv<<<dim3(32, 48), 256, 0, stream>>>(xb, wqb, Qb, Kb, Vtb);
  attn_kernel<<<512, 512, 0, stream>>>(Qb, Kb, Vtb, Yb);
  gemm_out<<<dim3(32, 16), 256, 0, stream>>>(Yb, wob, out);
}

// Round 16
// 241.050 us; speedup vs baseline: 2.1841x; 2.1841x over previous
//
#include <hip/hip_runtime.h>
#include <stdint.h>

// SoftmaxAttention: x[2,2048,2048] f32, w_qkv[6144,2048] f32, w_out[2048,2048] f32
// out[2,2048,2048] f32.  All matmul-shaped compute via bf16 MFMA 16x16x32.
// R16 = R14 verbatim (best measured config, 241.1 us).  R15's launch_bounds
// (256,5) experiment spilled (VGPR 116->48, WRITE_SIZE 49->913 MB): reverted.

typedef __attribute__((ext_vector_type(8))) short bf16x8;
typedef __attribute__((ext_vector_type(8))) unsigned short u16x8;
typedef __attribute__((ext_vector_type(4))) unsigned short u16x4;
typedef __attribute__((ext_vector_type(4))) float f32x4;

#define MFMA16(a, b, c) __builtin_amdgcn_mfma_f32_16x16x32_bf16((a), (b), (c), 0, 0, 0)

__device__ __forceinline__ unsigned short f2bf(float f) {
  union { float f; uint32_t u; } v; v.f = f;
  uint32_t r = v.u + 0x7FFFu + ((v.u >> 16) & 1u);  // RNE
  return (unsigned short)(r >> 16);
}

__device__ __forceinline__ void gld_lds16(const unsigned short* g, unsigned short* lds) {
  __builtin_amdgcn_global_load_lds(
      (const __attribute__((address_space(1))) void*)g,
      (__attribute__((address_space(3))) void*)lds, 16, 0, 0);
}

// ---------------------------------------------------------------- cvt f32->bf16
__device__ __forceinline__ void cvt8(const float* __restrict__ in,
                                     unsigned short* __restrict__ out, int i) {
  float4 a = reinterpret_cast<const float4*>(in)[i * 2];
  float4 b = reinterpret_cast<const float4*>(in)[i * 2 + 1];
  u16x8 o;
  o[0] = f2bf(a.x); o[1] = f2bf(a.y); o[2] = f2bf(a.z); o[3] = f2bf(a.w);
  o[4] = f2bf(b.x); o[5] = f2bf(b.y); o[6] = f2bf(b.z); o[7] = f2bf(b.w);
  reinterpret_cast<u16x8*>(out)[i] = o;
}

__global__ __launch_bounds__(256) void cvt_all(const float* __restrict__ x,
                                               const float* __restrict__ wq,
                                               const float* __restrict__ wo,
                                               unsigned short* __restrict__ xb,
                                               unsigned short* __restrict__ wqb,
                                               unsigned short* __restrict__ wob) {
  const int stride = gridDim.x * blockDim.x;
  const int t0 = blockIdx.x * blockDim.x + threadIdx.x;
  for (int i = t0; i < 1048576; i += stride) cvt8(x, xb, i);
  for (int i = t0; i < 1572864; i += stride) cvt8(wq, wqb, i);
  for (int i = t0; i < 524288; i += stride) cvt8(wo, wob, i);
}

// ============== 128x128 bf16 GEMM core, BK=64 single-buffer (B^T) =============
// 256 thr, 4 waves (2x2 of 64x64).  Per K-step(64): 8 gld_lds + barrier +
// (8 ds_read + 16 MFMA) x2 + barrier.  T2 swizzle g_lds = g ^ (row&7), via
// pre-swizzled global source (rule #21) + XOR'd fragment read: 0 conflicts.
__device__ __forceinline__ void gemm128_core(const unsigned short* __restrict__ A,
                                             const unsigned short* __restrict__ Bt,
                                             int K, int brow, int bcol,
                                             unsigned short* lds_a, unsigned short* lds_b,
                                             f32x4 acc[4][4]) {
  const int tid = threadIdx.x;
  const int l   = tid & 63;
  const int w   = tid >> 6;
  const int wr  = (w >> 1) << 6;
  const int wc  = (w & 1) << 6;

  const int srow = tid >> 3;
  const int gsrc = (tid & 7) ^ (srow & 7);
  const unsigned short* gA0 = A  + (size_t)(brow + srow) * K + 8 * gsrc;
  const unsigned short* gB0 = Bt + (size_t)(bcol + srow) * K + 8 * gsrc;
  unsigned short* dA0 = lds_a + tid * 8;
  unsigned short* dB0 = lds_b + tid * 8;

  const int fm = l & 15;
  const int q  = l >> 4;

  for (int k0 = 0; k0 < K; k0 += 64) {
#pragma unroll
    for (int c = 0; c < 4; c++)
      gld_lds16(gA0 + (size_t)c * 32 * K + k0, dA0 + c * 2048);
#pragma unroll
    for (int c = 0; c < 4; c++)
      gld_lds16(gB0 + (size_t)c * 32 * K + k0, dB0 + c * 2048);
    __syncthreads();  // drains vmcnt(0): staged data visible
#pragma unroll
    for (int ks = 0; ks < 2; ks++) {
      const int goff = 8 * ((ks * 4 + q) ^ (fm & 7));
      bf16x8 af[4], bfv[4];
#pragma unroll
      for (int i = 0; i < 4; i++)
        af[i] = *(const bf16x8*)&lds_a[(wr + i * 16 + fm) * 64 + goff];
#pragma unroll
      for (int j = 0; j < 4; j++)
        bfv[j] = *(const bf16x8*)&lds_b[(wc + j * 16 + fm) * 64 + goff];
#pragma unroll
      for (int i = 0; i < 4; i++)
#pragma unroll
        for (int j = 0; j < 4; j++)
          acc[i][j] = MFMA16(af[i], bfv[j], acc[i][j]);
    }
    __syncthreads();
  }
}

// --------------------------------------------------------------- QKV projection
// Grid dim3(32,48): blockIdx.x (fastest) = brow -> consecutive blocks share the
// SAME B panel.  No launch_bounds min-wave arg: VGPR 116 / 4 waves-SIMD is the
// verified optimum (5-wave cap spills, R15).
__global__ __launch_bounds__(256) void gemm_qkv(const unsigned short* __restrict__ xb,
                                                const unsigned short* __restrict__ wqb,
                                                unsigned short* __restrict__ Qb,
                                                unsigned short* __restrict__ Kb,
                                                unsigned short* __restrict__ Vtb) {
  __shared__ alignas(16) unsigned short lds_a[128 * 64];
  __shared__ alignas(16) unsigned short lds_b[128 * 64];
  f32x4 acc[4][4];
#pragma unroll
  for (int i = 0; i < 4; i++)
#pragma unroll
    for (int j = 0; j < 4; j++) acc[i][j] = (f32x4){0.f, 0.f, 0.f, 0.f};

  const int brow = blockIdx.x << 7;   // 32 row tiles (fastest-varying)
  const int bcol = blockIdx.y << 7;   // 48 col tiles
  gemm128_core(xb, wqb, 2048, brow, bcol, lds_a, lds_b, acc);

  const int l = threadIdx.x & 63;
  const int w = threadIdx.x >> 6;
  const int wr = (w >> 1) << 6, wc = (w & 1) << 6;
  const int which = bcol >> 11;                         // 0=Q 1=K 2=V (block-uniform)
  const float qs = (which == 0) ? 0.12752585f : 1.0f;   // log2(e)/sqrt(128) into Q
  const int bh = ((brow >> 11) << 4) | ((bcol >> 7) & 15);
  const int tbase = (brow & 2047) + wr + ((l >> 4) << 2);

#pragma unroll
  for (int i = 0; i < 4; i++) {
    const int t0 = tbase + i * 16;
#pragma unroll
    for (int j = 0; j < 4; j++) {
      const int d = wc + j * 16 + (l & 15);
      if (which == 2) {
        u16x4 pk;
#pragma unroll
        for (int r = 0; r < 4; r++) pk[r] = f2bf(acc[i][j][r]);
        *reinterpret_cast<u16x4*>(&Vtb[((size_t)bh * 128 + d) * 2048 + t0]) = pk;
      } else {
        unsigned short* dst = (which == 0 ? Qb : Kb) + ((size_t)bh * 2048 + t0) * 128 + d;
#pragma unroll
        for (int r = 0; r < 4; r++) dst[(size_t)r * 128] = f2bf(acc[i][j][r] * qs);
      }
    }
  }
}

// -------------------------------------------------------------- output projection
// Grid dim3(32,16): brow fastest -> consecutive blocks share the w_out panel.
__global__ __launch_bounds__(256) void gemm_out(const unsigned short* __restrict__ yb,
                                                const unsigned short* __restrict__ wob,
                                                float* __restrict__ out) {
  __shared__ alignas(16) unsigned short lds_a[128 * 64];
  __shared__ alignas(16) unsigned short lds_b[128 * 64];
  f32x4 acc[4][4];
#pragma unroll
  for (int i = 0; i < 4; i++)
#pragma unroll
    for (int j = 0; j < 4; j++) acc[i][j] = (f32x4){0.f, 0.f, 0.f, 0.f};

  const int brow = blockIdx.x << 7;   // 32 row tiles (fastest-varying)
  const int bcol = blockIdx.y << 7;   // 16 col tiles
  gemm128_core(yb, wob, 2048, brow, bcol, lds_a, lds_b, acc);

  const int l = threadIdx.x & 63;
  const int w = threadIdx.x >> 6;
  const int wr = (w >> 1) << 6, wc = (w & 1) << 6;
#pragma unroll
  for (int i = 0; i < 4; i++) {
    const int m0 = brow + wr + i * 16 + ((l >> 4) << 2);
#pragma unroll
    for (int j = 0; j < 4; j++) {
      const int n = bcol + wc + j * 16 + (l & 15);
#pragma unroll
      for (int r = 0; r < 4; r++) out[(size_t)(m0 + r) * 2048 + n] = acc[i][j][r];
    }
  }
}

// ------------------------------------------------------------------ flash attn
// 8-wave split of the causal pair: waves 0-3 own tile j, waves 4-7 own 31-j.
// K,V double-buffered; one vmcnt(0)+barrier per kv-step.  Defer-max + deferred
// sum.  Q pre-scaled; P stored by truncation; P-slot bijection; reciprocal
// epilogue.
__device__ __forceinline__ void stage_kv64(const unsigned short* __restrict__ Kg,
                                           const unsigned short* __restrict__ Vg,
                                           int kv0, unsigned short* dk,
                                           unsigned short* dv, int tid) {
#pragma unroll
  for (int c = 0; c < 2; c++) {
    int s = c * 512 + tid;
    int row = s >> 4, g = s & 15;
    gld_lds16(&Kg[(size_t)(kv0 + row) * 128 + 8 * (g ^ (row & 7))], &dk[s * 8]);
  }
#pragma unroll
  for (int c = 0; c < 2; c++) {
    int s = c * 512 + tid;
    int row = s >> 3, g = s & 7;
    gld_lds16(&Vg[(size_t)row * 2048 + kv0 + 8 * (g ^ (row & 7))], &dv[s * 8]);
  }
}

// one q-tile's contribution for one kv-tile (QK^T -> online softmax -> PV)
__device__ __forceinline__ void attn_tile_step(const bf16x8 qf[4], f32x4 yacc[8],
                                               float mrow[4], float lsum[4],
                                               int qw0, int kv0,
                                               const unsigned short* kb,
                                               const unsigned short* vb,
                                               unsigned short* pw, int l) {
  // S = Q K^T : 16 MFMA (Q pre-scaled by log2(e)/sqrt(128))
  f32x4 sfr[4];
  __builtin_amdgcn_s_setprio(1);
#pragma unroll
  for (int kt = 0; kt < 4; kt++) {
    const int kr = kt * 16 + (l & 15);
    f32x4 s4 = (f32x4){0.f, 0.f, 0.f, 0.f};
#pragma unroll
    for (int ds = 0; ds < 4; ds++) {
      bf16x8 kfr = *(const bf16x8*)&kb[kr * 128 + 8 * (((ds << 2) + (l >> 4)) ^ (kr & 7))];
      s4 = MFMA16(qf[ds], kfr, s4);
    }
    sfr[kt] = s4;
  }
  __builtin_amdgcn_s_setprio(0);
  const bool need_mask = (kv0 + 63 > qw0);
  if (need_mask) {
#pragma unroll
    for (int kt = 0; kt < 4; kt++)
#pragma unroll
      for (int r = 0; r < 4; r++) {
        int qa = qw0 + ((l >> 4) << 2) + r;
        int ka = kv0 + kt * 16 + (l & 15);
        if (ka > qa) sfr[kt][r] = -1e30f;
      }
  }
  // per-lane partial row max (rows at (l>>4)*4 + r, cols on l&15)
  float prmax[4];
#pragma unroll
  for (int r = 0; r < 4; r++)
    prmax[r] = fmaxf(fmaxf(sfr[0][r], sfr[1][r]), fmaxf(sfr[2][r], sfr[3][r]));
  // T13 defer-max, cheap per-lane check: skip shfl reduce AND rescale usually
  bool sm = (prmax[0] <= mrow[0] + 8.f) && (prmax[1] <= mrow[1] + 8.f) &&
            (prmax[2] <= mrow[2] + 8.f) && (prmax[3] <= mrow[3] + 8.f);
  if (!__all(sm)) {
    float f[4];
#pragma unroll
    for (int r = 0; r < 4; r++) {
      float m = prmax[r];
      m = fmaxf(m, __shfl_xor(m, 1));
      m = fmaxf(m, __shfl_xor(m, 2));
      m = fmaxf(m, __shfl_xor(m, 4));
      m = fmaxf(m, __shfl_xor(m, 8));
      float mn = fmaxf(mrow[r], m);
      f[r] = exp2f(mrow[r] - mn);   // row-uniform across the 16 lanes of a row
      mrow[r] = mn;
      lsum[r] *= f[r];
    }
#pragma unroll
    for (int dt = 0; dt < 8; dt++)
#pragma unroll
      for (int r = 0; r < 4; r++) yacc[dt][r] *= f[r];
  }
  // P = exp2(S - m) (bounded by 2^8 when deferred); per-lane deferred sum;
  // bf16 by truncation.  Slot = (k>>3) ^ ((row>>2)<<1): 8 slots/batch.
#pragma unroll
  for (int kt = 0; kt < 4; kt++)
#pragma unroll
    for (int r = 0; r < 4; r++) {
      float p = exp2f(sfr[kt][r] - mrow[r]);
      lsum[r] += p;
      union { float f; uint32_t u; } cc; cc.f = p;
      int row = ((l >> 4) << 2) + r;
      int k = kt * 16 + (l & 15);
      pw[row * 64 + (((k >> 3) ^ ((row >> 2) << 1)) << 3) + (k & 7)] =
          (unsigned short)(cc.u >> 16);
    }
  // cross-lane LDS write->read fence (same wave); rule #18 sched_barrier
  asm volatile("s_waitcnt lgkmcnt(0)" ::: "memory");
  __builtin_amdgcn_sched_barrier(0);
  // PV: 16 MFMA.  A = P, B = V from V^T LDS
  __builtin_amdgcn_s_setprio(1);
#pragma unroll
  for (int ks = 0; ks < 2; ks++) {
    const int prow = l & 15;
    bf16x8 pa = *(const bf16x8*)&pw[prow * 64 +
                                    (((ks * 4 + (l >> 4)) ^ ((prow >> 2) << 1)) << 3)];
#pragma unroll
    for (int dt = 0; dt < 8; dt++) {
      const int d = dt * 16 + (l & 15);
      bf16x8 vv = *(const bf16x8*)&vb[d * 64 + ((((ks << 2) + (l >> 4)) ^ (d & 7)) << 3)];
      yacc[dt] = MFMA16(pa, vv, yacc[dt]);
    }
  }
  __builtin_amdgcn_s_setprio(0);
}

__global__ __launch_bounds__(512, 4) void attn_kernel(const unsigned short* __restrict__ Qb,
                                                      const unsigned short* __restrict__ Kb,
                                                      const unsigned short* __restrict__ Vtb,
                                                      unsigned short* __restrict__ Yb) {
  __shared__ alignas(16) unsigned short lds_k[2][64 * 128];
  __shared__ alignas(16) unsigned short lds_v[2][128 * 64];
  __shared__ alignas(16) unsigned short p_lds[8][16 * 64];  // one per wave

  const int tid = threadIdx.x;
  const int l = tid & 63;
  const int w = tid >> 6;                    // 0..7

  const int bid = blockIdx.x;                // 0..511
  const int xcd = bid & 7;
  const int loc = bid >> 3;                  // 0..63
  const int bh = xcd * 4 + (loc >> 4);       // 0..31 (XCD-grouped KV)
  // complementary length pairing: loc and loc+32 get jidx j and 15-j
  const int jraw = loc & 15;
  const int jidx = (loc < 32) ? jraw : (15 - jraw);

  const int b = bh >> 4, h = bh & 15;

  const unsigned short* Qg = Qb + (size_t)bh * 2048 * 128;
  const unsigned short* Kg = Kb + (size_t)bh * 2048 * 128;
  const unsigned short* Vg = Vtb + (size_t)bh * 128 * 2048;

  // waves 0-3: tile jidx (rows (w&3)*16); waves 4-7: tile 31-jidx
  const int my_j = (w < 4) ? jidx : (31 - jidx);
  const int qw0 = (my_j << 6) + ((w & 3) << 4);

  // Q fragments (A-operand: m = l&15, k = ds*32 + 8*(l>>4))
  bf16x8 qf[4];
#pragma unroll
  for (int ds = 0; ds < 4; ds++)
    qf[ds] = *(const bf16x8*)&Qg[(size_t)(qw0 + (l & 15)) * 128 + ds * 32 + 8 * (l >> 4)];

  f32x4 yacc[8];
#pragma unroll
  for (int dt = 0; dt < 8; dt++) yacc[dt] = (f32x4){0.f, 0.f, 0.f, 0.f};
  float mrow[4], lsum[4];
#pragma unroll
  for (int r = 0; r < 4; r++) { mrow[r] = -1e30f; lsum[r] = 0.f; }

  const int nkv = (31 - jidx) + 1;  // hi tile bound: 17..32 kv-steps

  // prologue: stage tile 0
  stage_kv64(Kg, Vg, 0, lds_k[0], lds_v[0], tid);
  asm volatile("s_waitcnt vmcnt(0)" ::: "memory");
  __syncthreads();

  for (int t = 0; t < nkv; t++) {
    const int kv0 = t << 6;
    const int buf = t & 1;
    if (t + 1 < nkv)
      stage_kv64(Kg, Vg, kv0 + 64, lds_k[buf ^ 1], lds_v[buf ^ 1], tid);

    // hi waves: always active; lo waves: active while kv0 <= qw0+15
    if (kv0 <= qw0 + 15)
      attn_tile_step(qf, yacc, mrow, lsum, qw0, kv0, lds_k[buf], lds_v[buf],
                     p_lds[w], l);

    asm volatile("s_waitcnt vmcnt(0)" ::: "memory");
    __syncthreads();
  }

  // epilogue: reduce deferred sum once, reciprocal, then y into [B,T,C]
  float rinv[4];
#pragma unroll
  for (int r = 0; r < 4; r++) {
    float s = lsum[r];
    s += __shfl_xor(s, 1); s += __shfl_xor(s, 2);
    s += __shfl_xor(s, 4); s += __shfl_xor(s, 8);
    rinv[r] = 1.0f / s;
  }
#pragma unroll
  for (int dt = 0; dt < 8; dt++)
#pragma unroll
    for (int r = 0; r < 4; r++) {
      int qa = qw0 + ((l >> 4) << 2) + r;
      Yb[((size_t)(b * 2048 + qa)) * 2048 + h * 128 + dt * 16 + (l & 15)] =
          f2bf(yacc[dt][r] * rinv[r]);
    }
}

// ---------------------------------------------------------------------- launch
extern "C" void kernel_launch(void* const* d_in, const int* in_sizes, int n_in,
                              void* d_out, int out_size, void* d_ws, size_t ws_size,
                              hipStream_t stream) {
  const float* x    = (const float*)d_in[0];
  const float* wqkv = (const float*)d_in[1];
  const float* wout = (const float*)d_in[2];
  float* out = (float*)d_out;

  // workspace layout (bf16 elements)
  unsigned short* ws  = (unsigned short*)d_ws;
  unsigned short* xb  = ws;                        // 4096*2048
  unsigned short* wqb = xb + (size_t)8388608;      // 6144*2048
  unsigned short* wob = wqb + (size_t)12582912;    // 2048*2048
  unsigned short* Qb  = wob + (size_t)4194304;     // [32,2048,128] (pre-scaled)
  unsigned short* Kb  = Qb + (size_t)8388608;      // [32,2048,128]
  unsigned short* Vtb = Kb + (size_t)8388608;      // [32,128,2048] (transposed)
  unsigned short* Yb  = Vtb + (size_t)8388608;     // [4096,2048]

  cvt_all<<<2048, 256, 0, stream>>>(x, wqkv, wout, xb, wqb, wob);
  gemm_qkv<<<dim3(32, 48), 256, 0, stream>>>(xb, wqb, Qb, Kb, Vtb);
  attn_kernel<<<512, 512, 0, stream>>>(Qb, Kb, Vtb, Yb);
  gemm_out<<<dim3(32, 16), 256, 0, stream>>>(Yb, wob, out);
}